// Round 5
// baseline (363.828 us; speedup 1.0000x reference)
//
#include <hip/hip_runtime.h>
#include <cstdint>
#include <cstddef>

// Problem constants
#define B_  16
#define T_  2048
#define DIN 1024
#define DPJ 512
#define DOUT 1024
#define LORD 20
#define HALO (LORD - 1)             // 19
#define M_ROWS (B_ * T_)            // 32768
#define OUT0_ELEMS ((size_t)M_ROWS * DOUT)          // 33554432
#define CACHE_ELEMS ((size_t)B_ * DPJ * (LORD - 1)) // 155648

typedef __bf16 bf16_t;
typedef __bf16 bf16x2 __attribute__((ext_vector_type(2)));
typedef __bf16 bf16x4 __attribute__((ext_vector_type(4)));
typedef __bf16 bf16x8 __attribute__((ext_vector_type(8)));
typedef float  f32x4  __attribute__((ext_vector_type(4)));

// ---------------------------------------------------------------------------
// async global->LDS, 16B per lane. lds pointer must be wave-uniform; HW puts
// lane i's 16B at lds_base + i*16.
__device__ __forceinline__ void async_load16(const void* g, void* lds_base) {
    __builtin_amdgcn_global_load_lds(
        (const __attribute__((address_space(1))) unsigned int*)g,
        (__attribute__((address_space(3))) unsigned int*)lds_base,
        16, 0, 0);
}

// ---------------------------------------------------------------------------
// XCD-aware bijective block swizzle (T1). Round-1 evidence: FETCH_SIZE
// 265MB -> 74MB on gemm1. Keep. Requires nwg % 8 == 0 (1024/2048 here).
__device__ __forceinline__ int xcd_swizzle(int hw, int nwg) {
    int cpx = nwg >> 3;                  // chunk per XCD
    return (hw & 7) * cpx + (hw >> 3);
}

// ---------------------------------------------------------------------------
// Both weight transposes in one launch.
// W_lin (DIN x DPJ) -> WlT (DPJ x DIN) bf16 ; W_aff (DPJ x DOUT) -> WaT (DOUT x DPJ)
__global__ __launch_bounds__(256) void prep_weights(
    const float* __restrict__ Wl, const float* __restrict__ Wa,
    bf16_t* __restrict__ WlT, bf16_t* __restrict__ WaT) {
    int idx = blockIdx.x * 256 + threadIdx.x;
    const int n1 = DIN * DPJ;
    if (idx < n1) {
        int k = idx / DPJ, n = idx - k * DPJ;
        WlT[(size_t)n * DIN + k] = (bf16_t)Wl[idx];
    } else {
        int j = idx - n1;
        if (j < DPJ * DOUT) {
            int k = j / DOUT, n = j - k * DOUT;
            WaT[(size_t)n * DPJ + k] = (bf16_t)Wa[j];
        }
    }
}

// ---------------------------------------------------------------------------
// GEMM1: C_bf16[M,N] = bf16(A_f32[M,K]) * Bt[N,K]^T.
// Round-5: occupancy restructure. Round-4 evidence: VGPR 76 + AGPR 64 = 140
// regs -> 8 waves/CU (m69 bracket), latency-bound at MfmaUtil 15%. New
// geometry: 512-thread block, same 128x128 tile, wave sub-tile 64x32 ->
// acc[4][2] = 32 AGPR, A-prefetch 16 VGPR (1 row/thread). Total ~100 regs
// < 128 -> 16 waves/CU, enforced by __launch_bounds__(512, 4).
// Counted-vmcnt pipeline kept: B DMA first, cvt+write A(k) from prev-iter
// regs, issue A(k+1), s_waitcnt vmcnt(4) drains only the 2 B DMAs.
// Raw barriers bracketed by sched_barrier(0) (rule #18).
__global__ __launch_bounds__(512, 4) void gemm1_fused(
    const float* __restrict__ A, const bf16_t* __restrict__ Bt,
    bf16_t* __restrict__ C, const int M, const int N, const int K) {
    __shared__ bf16_t sA[128 * 64];   // 16 KB
    __shared__ bf16_t sB[128 * 64];   // 16 KB

    const int tid  = threadIdx.x;
    const int lane = tid & 63;
    const int wave = tid >> 6;           // 0..7

    // XCD-aware remap of the block id (hw linear order is x-fastest).
    const int gx   = gridDim.x;
    const int hw   = blockIdx.y * gx + blockIdx.x;
    const int lid  = xcd_swizzle(hw, gx * gridDim.y);
    const int lby  = lid / gx;
    const int lbx  = lid - lby * gx;
    const int col0 = lbx * 128;          // N tile (fastest-varying logically)
    const int row0 = lby * 128;          // M tile

    // ---- A reg-stage: 1 row per thread (512 thr x 16 f32 = 128x64 tile) ----
    // s4 in 0..3 selects bf16-chunks j=s4 and j=s4+4 (f32 [8s4,8s4+8) and
    // [8s4+32,8s4+40)).  Swizzled store: chunk j lands at j^(arow&7).
    const int s4   = tid & 3;
    const int arow = tid >> 2;           // 0..127
    const float* gA = A + (size_t)(row0 + arow) * K + s4 * 8;
    const int o0 = ((s4       ^ (arow & 7)) << 3);
    const int o1 = (((s4 + 4) ^ (arow & 7)) << 3);
    bf16_t* dst0 = sA + arow * 64;

    // ---- B staging: 2 async calls/thread; wave w covers rows w*16+c*8+lr ----
    const int lr  = lane >> 3;
    const int jsw = (lane & 7) ^ lr;
    const bf16_t* gB0 = Bt + (size_t)(col0 + wave * 16 + lr) * K + jsw * 8;
    bf16_t* lB0 = sB + wave * 1024;      // 16 rows x 64 elems per wave

    // compute-side: wave -> 64x32 sub-tile (2 M-waves x 4 N-waves)
    const int wm = (wave >> 2) * 64;
    const int wn = (wave & 3) * 32;
    const int fr = lane & 15;
    const int fk = lane >> 4;

    const f32x4 zero = {0.f, 0.f, 0.f, 0.f};
    f32x4 acc[4][2];
#pragma unroll
    for (int mt = 0; mt < 4; ++mt)
#pragma unroll
        for (int nt = 0; nt < 2; ++nt) acc[mt][nt] = zero;

    // ---- prologue: issue A(0) loads ----
    f32x4 g0a, g0b, g0c, g0d;
    g0a = *(const f32x4*)(gA);
    g0b = *(const f32x4*)(gA + 4);
    g0c = *(const f32x4*)(gA + 32);
    g0d = *(const f32x4*)(gA + 36);

    for (int k0 = 0; k0 < K; k0 += 64) {
        // all waves done reading LDS tile k-1
        asm volatile("s_waitcnt lgkmcnt(0)" ::: "memory");
        __builtin_amdgcn_sched_barrier(0);
        __builtin_amdgcn_s_barrier();
        __builtin_amdgcn_sched_barrier(0);

        // B DMA first: oldest vmem ops of this iteration (after prev A).
#pragma unroll
        for (int c = 0; c < 2; ++c)
            async_load16(gB0 + (size_t)c * 8 * K + k0, lB0 + c * 512);

        // cast + swizzled LDS write of A(k0) from regs (compiler inserts
        // the vmcnt wait for the A loads issued last iteration; the 2 B
        // DMAs above are newer and stay outstanding).
        {
            bf16x8 v0 = { (bf16_t)g0a[0], (bf16_t)g0a[1], (bf16_t)g0a[2], (bf16_t)g0a[3],
                          (bf16_t)g0b[0], (bf16_t)g0b[1], (bf16_t)g0b[2], (bf16_t)g0b[3] };
            bf16x8 v1 = { (bf16_t)g0c[0], (bf16_t)g0c[1], (bf16_t)g0c[2], (bf16_t)g0c[3],
                          (bf16_t)g0d[0], (bf16_t)g0d[1], (bf16_t)g0d[2], (bf16_t)g0d[3] };
            *(bf16x8*)(dst0 + o0) = v0;
            *(bf16x8*)(dst0 + o1) = v1;
        }

        const int kn = k0 + 64;
        if (kn < K) {
            // prefetch A(kn): lands during the compute phase.
            g0a = *(const f32x4*)(gA + kn);
            g0b = *(const f32x4*)(gA + kn + 4);
            g0c = *(const f32x4*)(gA + kn + 32);
            g0d = *(const f32x4*)(gA + kn + 36);
            // outstanding: 2 B DMA (old) + 4 A (new). Drain only the B's.
            asm volatile("s_waitcnt vmcnt(4) lgkmcnt(0)" ::: "memory");
        } else {
            asm volatile("s_waitcnt vmcnt(0) lgkmcnt(0)" ::: "memory");
        }
        __builtin_amdgcn_sched_barrier(0);
        __builtin_amdgcn_s_barrier();
        __builtin_amdgcn_sched_barrier(0);

        // compute phase: 64x32 per wave, 16 MFMA per K-step
#pragma unroll
        for (int h = 0; h < 2; ++h) {
            bf16x8 af[4], bfr[2];
#pragma unroll
            for (int mt = 0; mt < 4; ++mt) {
                int r = wm + mt * 16 + fr;
                int j = h * 4 + fk;
                af[mt] = *(const bf16x8*)(sA + r * 64 + ((j ^ (r & 7)) << 3));
            }
#pragma unroll
            for (int nt = 0; nt < 2; ++nt) {
                int r = wn + nt * 16 + fr;
                int j = h * 4 + fk;
                bfr[nt] = *(const bf16x8*)(sB + r * 64 + ((j ^ (r & 7)) << 3));
            }
#pragma unroll
            for (int mt = 0; mt < 4; ++mt)
#pragma unroll
                for (int nt = 0; nt < 2; ++nt)
                    acc[mt][nt] = __builtin_amdgcn_mfma_f32_16x16x32_bf16(
                        af[mt], bfr[nt], acc[mt][nt], 0, 0, 0);
        }
    }

    // epilogue: C/D layout col=lane&15, row=(lane>>4)*4+reg  [m89]
    const int er = row0 + wm + (lane >> 4) * 4;
    const int ec = col0 + wn + (lane & 15);
#pragma unroll
    for (int mt = 0; mt < 4; ++mt)
#pragma unroll
        for (int nt = 0; nt < 2; ++nt)
#pragma unroll
            for (int rr = 0; rr < 4; ++rr)
                C[(size_t)(er + mt * 16 + rr) * N + (ec + nt * 16)] =
                    (bf16_t)acc[mt][nt][rr];
}

// ---------------------------------------------------------------------------
// GEMM2: bf16 A (async staging), f32 out with bias+ReLU.
// Round-5: same occupancy restructure as gemm1 — 512-thread block, 128x128
// tile, wave 64x32, acc[4][2]=32 AGPR, __launch_bounds__(512,4) -> 16
// waves/CU.  Pure global_load_lds staging, simple 2-barrier loop.
__global__ __launch_bounds__(512, 4) void gemm_bt_relu(
    const bf16_t* __restrict__ A, const bf16_t* __restrict__ Bt,
    float* __restrict__ C, const float* __restrict__ bias,
    const int M, const int N, const int K) {
    __shared__ bf16_t sA[128 * 64];
    __shared__ bf16_t sB[128 * 64];

    const int tid  = threadIdx.x;
    const int lane = tid & 63;
    const int wave = tid >> 6;           // 0..7

    const int gx   = gridDim.x;
    const int hw   = blockIdx.y * gx + blockIdx.x;
    const int lid  = xcd_swizzle(hw, gx * gridDim.y);
    const int lby  = lid / gx;
    const int lbx  = lid - lby * gx;
    const int col0 = lbx * 128;          // N tile
    const int row0 = lby * 128;          // M tile

    // staging: wave w covers rows w*16 + c*8 + lr for c=0,1 (A and B alike)
    const int lr   = lane >> 3;
    const int jsw  = (lane & 7) ^ lr;
    const bf16_t* gA0 = A  + (size_t)(row0 + wave * 16 + lr) * K + jsw * 8;
    const bf16_t* gB0 = Bt + (size_t)(col0 + wave * 16 + lr) * K + jsw * 8;
    bf16_t* lA0 = sA + wave * 1024;
    bf16_t* lB0 = sB + wave * 1024;

    const int wm = (wave >> 2) * 64;
    const int wn = (wave & 3) * 32;
    const int fr = lane & 15;
    const int fk = lane >> 4;

    const f32x4 zero = {0.f, 0.f, 0.f, 0.f};
    f32x4 acc[4][2];
#pragma unroll
    for (int mt = 0; mt < 4; ++mt)
#pragma unroll
        for (int nt = 0; nt < 2; ++nt) acc[mt][nt] = zero;

    for (int k0 = 0; k0 < K; k0 += 64) {
        __syncthreads();
#pragma unroll
        for (int c = 0; c < 2; ++c) {
            async_load16(gA0 + (size_t)c * 8 * K + k0, lA0 + c * 512);
            async_load16(gB0 + (size_t)c * 8 * K + k0, lB0 + c * 512);
        }
        __syncthreads();

#pragma unroll
        for (int h = 0; h < 2; ++h) {
            bf16x8 af[4], bfr[2];
#pragma unroll
            for (int mt = 0; mt < 4; ++mt) {
                int r = wm + mt * 16 + fr;
                int j = h * 4 + fk;
                af[mt] = *(const bf16x8*)(sA + r * 64 + ((j ^ (r & 7)) << 3));
            }
#pragma unroll
            for (int nt = 0; nt < 2; ++nt) {
                int r = wn + nt * 16 + fr;
                int j = h * 4 + fk;
                bfr[nt] = *(const bf16x8*)(sB + r * 64 + ((j ^ (r & 7)) << 3));
            }
#pragma unroll
            for (int mt = 0; mt < 4; ++mt)
#pragma unroll
                for (int nt = 0; nt < 2; ++nt)
                    acc[mt][nt] = __builtin_amdgcn_mfma_f32_16x16x32_bf16(
                        af[mt], bfr[nt], acc[mt][nt], 0, 0, 0);
        }
    }

    const int er = row0 + wm + (lane >> 4) * 4;
    const int ec = col0 + wn + (lane & 15);
#pragma unroll
    for (int nt = 0; nt < 2; ++nt) {
        float bb = bias[ec + nt * 16];
#pragma unroll
        for (int mt = 0; mt < 4; ++mt)
#pragma unroll
            for (int rr = 0; rr < 4; ++rr) {
                float v = acc[mt][nt][rr] + bb;
                C[(size_t)(er + mt * 16 + rr) * N + (ec + nt * 16)] =
                    v > 0.f ? v : 0.f;
            }
    }
}

// ---------------------------------------------------------------------------
// Depthwise causal conv + residual, LDS-tiled, rolling register window.
// Last-t blocks also emit out_cache from their staged LDS (f32).
#define TT 64
#define PPT 128
__global__ __launch_bounds__(256) void dwconv_tiled(
    const bf16_t* __restrict__ x, const float* __restrict__ cache,
    const float* __restrict__ cw, bf16_t* __restrict__ m,
    float* __restrict__ oc) {
    __shared__ float sx[(TT + HALO) * PPT];   // 83*128*4 = 42.5 KB

    const int tid = threadIdx.x;
    const int t0  = blockIdx.x * TT;
    const int b   = blockIdx.y;
    const int p0  = blockIdx.z * PPT;

    // ---- stage rows t0-19 .. t0+63, cols p0..p0+127 (8 bf16 per chunk) ----
    for (int c = tid; c < (TT + HALO) * PPT / 8; c += 256) {   // 1328 chunks
        int r    = c >> 4;            // 0..82
        int col  = (c & 15) << 3;     // 0,8,...,120
        int trow = t0 - HALO + r;
        float* dst = sx + r * PPT + col;
        if (trow >= 0) {
            bf16x8 v = *(const bf16x8*)(x + ((size_t)(b * T_ + trow)) * DPJ + p0 + col);
#pragma unroll
            for (int i = 0; i < 8; ++i) dst[i] = (float)v[i];
        } else {
#pragma unroll
            for (int i = 0; i < 8; ++i)
                dst[i] = cache[((size_t)b * DPJ + p0 + col + i) * HALO + (trow + HALO)];
        }
    }
    __syncthreads();

    // ---- compute: thread -> channel pair, 16 timesteps, rolling window ----
    const int pp   = tid & 63;
    const int half = tid >> 6;
    const int tb   = half * 16;
    const float2* sx2 = (const float2*)sx;   // [83][64]

    const int pg = p0 + 2 * pp;
    float2 w[LORD];
#pragma unroll
    for (int l = 0; l < LORD; ++l) {
        w[l].x = cw[pg * LORD + l];
        w[l].y = cw[(pg + 1) * LORD + l];
    }

    float2 win[LORD];
#pragma unroll
    for (int i = 0; i < HALO; ++i) win[i] = sx2[(tb + i) * 64 + pp];

#pragma unroll
    for (int tl = 0; tl < 16; ++tl) {
        float2 nv = sx2[(tb + tl + HALO) * 64 + pp];
        win[(tl + HALO) % LORD] = nv;
        float2 s = nv;                         // residual x[b,t,p]
#pragma unroll
        for (int l = 0; l < LORD; ++l) {
            float2 v = win[(tl + l) % LORD];
            s.x += w[l].x * v.x;
            s.y += w[l].y * v.y;
        }
        bf16x2 o = { (bf16_t)s.x, (bf16_t)s.y };
        *(bf16x2*)(m + ((size_t)(b * T_ + t0 + tb + tl)) * DPJ + pg) = o;
    }

    // ---- fused out_cache: out_cache[b,p,j] = x[b, T-19+j, p], from LDS ----
    // Last t-tile has rows T-19..T-1 staged at r = 64..82.
    if (blockIdx.x == (T_ / TT) - 1) {
        for (int i = tid; i < PPT * HALO; i += 256) {
            int pl = i / HALO;
            int j  = i - pl * HALO;
            oc[((size_t)b * DPJ + p0 + pl) * HALO + j] = sx[(64 + j) * PPT + pl];
        }
    }
}

// ---------------------------------------------------------------------------
extern "C" void kernel_launch(void* const* d_in, const int* in_sizes, int n_in,
                              void* d_out, int out_size, void* d_ws, size_t ws_size,
                              hipStream_t stream) {
    const float* input    = (const float*)d_in[0];  // (16,2048,1024)
    const float* in_cache = (const float*)d_in[1];  // (16,512,19)
    const float* W_lin    = (const float*)d_in[2];  // (1024,512)
    const float* conv_w   = (const float*)d_in[3];  // (512,20)
    const float* W_aff    = (const float*)d_in[4];  // (512,1024)
    const float* b_aff    = (const float*)d_in[5];  // (1024,)
    float* out = (float*)d_out;                     // 33554432 + 155648 f32

    // workspace layout (bytes):
    //   [0, 32MB)       x bf16 (32768x512)
    //   [32MB, 64MB)    m bf16 (32768x512)
    //   [64MB, +1MB)    W_lin^T bf16 (512x1024)
    //   [65MB, +0.5MB)  W_aff^T bf16 (1024x512)
    char* ws = (char*)d_ws;
    bf16_t* x_buf = (bf16_t*)(ws);
    bf16_t* m_buf = (bf16_t*)(ws + 33554432);
    bf16_t* WlinT = (bf16_t*)(ws + 67108864);
    bf16_t* WaffT = (bf16_t*)(ws + 67108864 + 1048576);

    // 1. weight prep (both transposes, one launch)
    prep_weights<<<(DIN * DPJ + DPJ * DOUT + 255) / 256, 256, 0, stream>>>(
        W_lin, W_aff, WlinT, WaffT);

    // 2. x = bf16(input) @ W_lin   (M=32768, N=512, K=1024), 512-thr blocks
    gemm1_fused<<<dim3(DPJ / 128, M_ROWS / 128), 512, 0, stream>>>(
        input, WlinT, x_buf, M_ROWS, DPJ, DIN);

    // 3. depthwise conv + residual -> m ; out_cache fused into last-t blocks
    dwconv_tiled<<<dim3(T_ / TT, B_, DPJ / PPT), 256, 0, stream>>>(
        x_buf, in_cache, conv_w, m_buf, out + OUT0_ELEMS);

    // 4. out = relu(m @ W_aff + b)  (M=32768, N=1024, K=512), 512-thr blocks
    gemm_bt_relu<<<dim3(DOUT / 128, M_ROWS / 128), 512, 0, stream>>>(
        m_buf, WaffT, out, b_aff, M_ROWS, DOUT, DPJ);
}

// Round 6
// 352.402 us; speedup vs baseline: 1.0324x; 1.0324x over previous
//
#include <hip/hip_runtime.h>
#include <cstdint>
#include <cstddef>

// Problem constants
#define B_  16
#define T_  2048
#define DIN 1024
#define DPJ 512
#define DOUT 1024
#define LORD 20
#define HALO (LORD - 1)             // 19
#define M_ROWS (B_ * T_)            // 32768
#define OUT0_ELEMS ((size_t)M_ROWS * DOUT)          // 33554432
#define CACHE_ELEMS ((size_t)B_ * DPJ * (LORD - 1)) // 155648

typedef __bf16 bf16_t;
typedef __bf16 bf16x2 __attribute__((ext_vector_type(2)));
typedef __bf16 bf16x4 __attribute__((ext_vector_type(4)));
typedef __bf16 bf16x8 __attribute__((ext_vector_type(8)));
typedef float  f32x4  __attribute__((ext_vector_type(4)));

// ---------------------------------------------------------------------------
// async global->LDS, 16B per lane. lds pointer must be wave-uniform; HW puts
// lane i's 16B at lds_base + i*16.
__device__ __forceinline__ void async_load16(const void* g, void* lds_base) {
    __builtin_amdgcn_global_load_lds(
        (const __attribute__((address_space(1))) unsigned int*)g,
        (__attribute__((address_space(3))) unsigned int*)lds_base,
        16, 0, 0);
}

// ---------------------------------------------------------------------------
// XCD-aware bijective block swizzle (T1). Round-1 evidence: FETCH_SIZE
// 265MB -> 74MB on gemm1. Keep. Requires nwg % 8 == 0 (1024/2048 here).
__device__ __forceinline__ int xcd_swizzle(int hw, int nwg) {
    int cpx = nwg >> 3;                  // chunk per XCD
    return (hw & 7) * cpx + (hw >> 3);
}

// ---------------------------------------------------------------------------
// Weight transposes. Round-6: flipped indexing — idx enumerates the OUTPUT
// element, so the 2B writes are coalesced (512B/wave) and the strided 4B
// reads hit L2 (Wl=2MB, Wa=2MB are cache-resident). Old version did 2B
// scattered writes at 2KB stride (32x write amplification through L2).
__global__ __launch_bounds__(256) void prep_weights(
    const float* __restrict__ Wl, const float* __restrict__ Wa,
    bf16_t* __restrict__ WlT, bf16_t* __restrict__ WaT) {
    int idx = blockIdx.x * 256 + threadIdx.x;
    const int n1 = DIN * DPJ;
    if (idx < n1) {
        // WlT is (DPJ x DIN): element idx -> n = idx/DIN, k = idx%DIN
        int n = idx >> 10;               // /DIN
        int k = idx - (n << 10);
        WlT[idx] = (bf16_t)Wl[(size_t)k * DPJ + n];
    } else {
        int j = idx - n1;
        if (j < DPJ * DOUT) {
            // WaT is (DOUT x DPJ): element j -> n = j/DPJ, k = j%DPJ
            int n = j >> 9;              // /DPJ
            int k = j - (n << 9);
            WaT[j] = (bf16_t)Wa[(size_t)k * DOUT + n];
        }
    }
}

// ---------------------------------------------------------------------------
// GEMM1: C_bf16[M,N] = bf16(A_f32[M,K]) * Bt[N,K]^T.
// Round-6: TRUE double-buffered pipeline. Rounds 2-5 evidence: every
// single-buffered variant lands at 86-97us with MfmaUtil 15% — the
// same-phase stage->compute dependency exposes L2/HBM latency once per
// K-step. Now: stage tile t+1 into buffer X while computing tile t from
// buffer Y; the only waits are on ops issued a FULL phase earlier:
//   top of iter: vmcnt(4) drains B(t) DMA (issued last iter, latency
//   hidden under compute(t-1)); keeps A(t+1) reg-loads (newest 4) flying.
//   A regs ping-pong P/Q so A(t+2) issues without WAR on A(t+1).
// One barrier per K-step. 64KB LDS -> 2 blocks/CU; pipeline is intra-block.
__global__ __launch_bounds__(512, 4) void gemm1_fused(
    const float* __restrict__ A, const bf16_t* __restrict__ Bt,
    bf16_t* __restrict__ C, const int M, const int N, const int K) {
    __shared__ bf16_t sA[2][128 * 64];   // 2 x 16 KB
    __shared__ bf16_t sB[2][128 * 64];   // 2 x 16 KB

    const int tid  = threadIdx.x;
    const int lane = tid & 63;
    const int wave = tid >> 6;           // 0..7

    const int gx   = gridDim.x;
    const int hw   = blockIdx.y * gx + blockIdx.x;
    const int lid  = xcd_swizzle(hw, gx * gridDim.y);
    const int lby  = lid / gx;
    const int lbx  = lid - lby * gx;
    const int col0 = lbx * 128;          // N tile
    const int row0 = lby * 128;          // M tile

    // ---- A reg-stage: 1 row/thread (512 thr x 16 f32 = 128x64 tile) ----
    const int s4   = tid & 3;
    const int arow = tid >> 2;           // 0..127
    const float* gA = A + (size_t)(row0 + arow) * K + s4 * 8;
    const int o0 = ((s4       ^ (arow & 7)) << 3);
    const int o1 = (((s4 + 4) ^ (arow & 7)) << 3);

    // ---- B staging: 2 async calls/wave; wave w covers rows w*16+c*8+lr ----
    const int lr  = lane >> 3;
    const int jsw = (lane & 7) ^ lr;
    const bf16_t* gB0 = Bt + (size_t)(col0 + wave * 16 + lr) * K + jsw * 8;

    // compute-side: wave -> 64x32 sub-tile
    const int wm = (wave >> 2) * 64;
    const int wn = (wave & 3) * 32;
    const int fr = lane & 15;
    const int fk = lane >> 4;

    const f32x4 zero = {0.f, 0.f, 0.f, 0.f};
    f32x4 acc[4][2];
#pragma unroll
    for (int mt = 0; mt < 4; ++mt)
#pragma unroll
        for (int nt = 0; nt < 2; ++nt) acc[mt][nt] = zero;

    f32x4 P[4], Q[4];                    // ping-pong A reg sets

    auto load_a = [&](f32x4* r, int kk) {
        r[0] = *(const f32x4*)(gA + kk);
        r[1] = *(const f32x4*)(gA + kk + 4);
        r[2] = *(const f32x4*)(gA + kk + 32);
        r[3] = *(const f32x4*)(gA + kk + 36);
    };
    auto cvt_write = [&](const f32x4* r, bf16_t* dstbuf) {
        bf16x8 v0 = { (bf16_t)r[0][0], (bf16_t)r[0][1], (bf16_t)r[0][2], (bf16_t)r[0][3],
                      (bf16_t)r[1][0], (bf16_t)r[1][1], (bf16_t)r[1][2], (bf16_t)r[1][3] };
        bf16x8 v1 = { (bf16_t)r[2][0], (bf16_t)r[2][1], (bf16_t)r[2][2], (bf16_t)r[2][3],
                      (bf16_t)r[3][0], (bf16_t)r[3][1], (bf16_t)r[3][2], (bf16_t)r[3][3] };
        *(bf16x8*)(dstbuf + arow * 64 + o0) = v0;
        *(bf16x8*)(dstbuf + arow * 64 + o1) = v1;
    };
    auto stage_b = [&](int kk, bf16_t* dstbuf) {
#pragma unroll
        for (int c = 0; c < 2; ++c)
            async_load16(gB0 + (size_t)c * 8 * K + kk, dstbuf + wave * 1024 + c * 512);
    };
    auto compute = [&](const bf16_t* bA, const bf16_t* bB) {
#pragma unroll
        for (int h = 0; h < 2; ++h) {
            bf16x8 af[4], bfr[2];
#pragma unroll
            for (int mt = 0; mt < 4; ++mt) {
                int r = wm + mt * 16 + fr;
                int j = h * 4 + fk;
                af[mt] = *(const bf16x8*)(bA + r * 64 + ((j ^ (r & 7)) << 3));
            }
#pragma unroll
            for (int nt = 0; nt < 2; ++nt) {
                int r = wn + nt * 16 + fr;
                int j = h * 4 + fk;
                bfr[nt] = *(const bf16x8*)(bB + r * 64 + ((j ^ (r & 7)) << 3));
            }
#pragma unroll
            for (int mt = 0; mt < 4; ++mt)
#pragma unroll
                for (int nt = 0; nt < 2; ++nt)
                    acc[mt][nt] = __builtin_amdgcn_mfma_f32_16x16x32_bf16(
                        af[mt], bfr[nt], acc[mt][nt], 0, 0, 0);
        }
    };

    // ---- prologue: tile 0 into buf0; A(1) into P ----
    load_a(P, 0);                // A(0)
    stage_b(0, sB[0]);           // B(0) DMA (stays in flight past cvt wait)
    cvt_write(P, sA[0]);         // implicit wait on A(0) only (cold, once)
    load_a(P, 64);               // A(1) -> P (reuse after consume)

    // steady state at each iter top: outstanding = B(t) 2 (old) + A(t+1) 4
    // (new).  vmcnt(4) drains exactly B(t).
    for (int k0 = 0; k0 < K; k0 += 128) {
        // ---- even tile t = k0/64: Y=0, X=1, CUR=P, OTH=Q ----
        asm volatile("s_waitcnt vmcnt(4) lgkmcnt(0)" ::: "memory");
        __builtin_amdgcn_sched_barrier(0);
        __builtin_amdgcn_s_barrier();
        __builtin_amdgcn_sched_barrier(0);
        {
            const int kn = k0 + 64;          // < K (k0 <= K-128)
            stage_b(kn, sB[1]);              // B(t+1) -> X
            cvt_write(P, sA[1]);             // A(t+1) -> X (regs from last iter)
            if (kn + 64 < K) load_a(Q, kn + 64);   // A(t+2)
        }
        compute(sA[0], sB[0]);

        // ---- odd tile t+1: Y=1, X=0, CUR=Q, OTH=P ----
        const int kn2 = k0 + 128;
        if (kn2 >= K) {
            asm volatile("s_waitcnt vmcnt(0) lgkmcnt(0)" ::: "memory");
        } else {
            asm volatile("s_waitcnt vmcnt(4) lgkmcnt(0)" ::: "memory");
        }
        __builtin_amdgcn_sched_barrier(0);
        __builtin_amdgcn_s_barrier();
        __builtin_amdgcn_sched_barrier(0);
        if (kn2 < K) {
            stage_b(kn2, sB[0]);             // B(t+2) -> buf0
            cvt_write(Q, sA[0]);             // A(t+2) -> buf0
            if (kn2 + 64 < K) load_a(P, kn2 + 64);
        }
        compute(sA[1], sB[1]);
    }

    // epilogue: C/D layout col=lane&15, row=(lane>>4)*4+reg  [m89]
    const int er = row0 + wm + (lane >> 4) * 4;
    const int ec = col0 + wn + (lane & 15);
#pragma unroll
    for (int mt = 0; mt < 4; ++mt)
#pragma unroll
        for (int nt = 0; nt < 2; ++nt)
#pragma unroll
            for (int rr = 0; rr < 4; ++rr)
                C[(size_t)(er + mt * 16 + rr) * N + (ec + nt * 16)] =
                    (bf16_t)acc[mt][nt][rr];
}

// ---------------------------------------------------------------------------
// GEMM2: bf16 A (async staging), f32 out with bias+ReLU.
// Round-6: 256-thr round-4 geometry (512-thr was the round-5 regression)
// + double-buffered 1-barrier pipeline: stage(t+1)->X after the barrier,
// compute(t)<-Y; vmcnt(0) at iter top waits on DMAs issued a full compute
// phase earlier (~0 stall).
__global__ __launch_bounds__(256) void gemm_bt_relu(
    const bf16_t* __restrict__ A, const bf16_t* __restrict__ Bt,
    float* __restrict__ C, const float* __restrict__ bias,
    const int M, const int N, const int K) {
    __shared__ bf16_t sA[2][128 * 64];
    __shared__ bf16_t sB[2][128 * 64];

    const int tid  = threadIdx.x;
    const int lane = tid & 63;
    const int wave = tid >> 6;           // 0..3

    const int gx   = gridDim.x;
    const int hw   = blockIdx.y * gx + blockIdx.x;
    const int lid  = xcd_swizzle(hw, gx * gridDim.y);
    const int lby  = lid / gx;
    const int lbx  = lid - lby * gx;
    const int col0 = lbx * 128;          // N tile
    const int row0 = lby * 128;          // M tile

    const int lr   = lane >> 3;
    const int jsw  = (lane & 7) ^ lr;
    const bf16_t* gA0 = A  + (size_t)(row0 + wave * 32 + lr) * K + jsw * 8;
    const bf16_t* gB0 = Bt + (size_t)(col0 + wave * 32 + lr) * K + jsw * 8;

    const int wm = (wave >> 1) * 64;
    const int wn = (wave & 1) * 64;
    const int fr = lane & 15;
    const int fk = lane >> 4;

    const f32x4 zero = {0.f, 0.f, 0.f, 0.f};
    f32x4 acc[4][4];
#pragma unroll
    for (int mt = 0; mt < 4; ++mt)
#pragma unroll
        for (int nt = 0; nt < 4; ++nt) acc[mt][nt] = zero;

    auto stage = [&](int kk, bf16_t* dA, bf16_t* dB) {
#pragma unroll
        for (int c = 0; c < 4; ++c) {
            async_load16(gA0 + (size_t)c * 8 * K + kk, dA + wave * 2048 + c * 512);
            async_load16(gB0 + (size_t)c * 8 * K + kk, dB + wave * 2048 + c * 512);
        }
    };
    auto compute = [&](const bf16_t* bA, const bf16_t* bB) {
#pragma unroll
        for (int h = 0; h < 2; ++h) {
            bf16x8 af[4], bfr[4];
#pragma unroll
            for (int mt = 0; mt < 4; ++mt) {
                int r = wm + mt * 16 + fr;
                int j = h * 4 + fk;
                af[mt] = *(const bf16x8*)(bA + r * 64 + ((j ^ (r & 7)) << 3));
            }
#pragma unroll
            for (int nt = 0; nt < 4; ++nt) {
                int r = wn + nt * 16 + fr;
                int j = h * 4 + fk;
                bfr[nt] = *(const bf16x8*)(bB + r * 64 + ((j ^ (r & 7)) << 3));
            }
#pragma unroll
            for (int mt = 0; mt < 4; ++mt)
#pragma unroll
                for (int nt = 0; nt < 4; ++nt)
                    acc[mt][nt] = __builtin_amdgcn_mfma_f32_16x16x32_bf16(
                        af[mt], bfr[nt], acc[mt][nt], 0, 0, 0);
        }
    };

    // prologue: tile 0 -> buf0 (no wait; first iter's vmcnt(0) handles it)
    stage(0, sA[0], sB[0]);

    for (int k0 = 0; k0 < K; k0 += 128) {
        // ---- even tile: compute buf0, stage t+1 -> buf1 ----
        asm volatile("s_waitcnt vmcnt(0)" ::: "memory");
        __builtin_amdgcn_sched_barrier(0);
        __builtin_amdgcn_s_barrier();
        __builtin_amdgcn_sched_barrier(0);
        stage(k0 + 64, sA[1], sB[1]);        // k0+64 < K always (k0 <= K-128)
        compute(sA[0], sB[0]);

        // ---- odd tile: compute buf1, stage t+2 -> buf0 ----
        asm volatile("s_waitcnt vmcnt(0)" ::: "memory");
        __builtin_amdgcn_sched_barrier(0);
        __builtin_amdgcn_s_barrier();
        __builtin_amdgcn_sched_barrier(0);
        const int kn2 = k0 + 128;
        if (kn2 < K) stage(kn2, sA[0], sB[0]);
        compute(sA[1], sB[1]);
    }

    const int er = row0 + wm + (lane >> 4) * 4;
    const int ec = col0 + wn + (lane & 15);
#pragma unroll
    for (int nt = 0; nt < 4; ++nt) {
        float bb = bias[ec + nt * 16];
#pragma unroll
        for (int mt = 0; mt < 4; ++mt)
#pragma unroll
            for (int rr = 0; rr < 4; ++rr) {
                float v = acc[mt][nt][rr] + bb;
                C[(size_t)(er + mt * 16 + rr) * N + (ec + nt * 16)] =
                    v > 0.f ? v : 0.f;
            }
    }
}

// ---------------------------------------------------------------------------
// Depthwise causal conv + residual, LDS-tiled, rolling register window.
// Last-t blocks also emit out_cache from their staged LDS (f32).
#define TT 64
#define PPT 128
__global__ __launch_bounds__(256) void dwconv_tiled(
    const bf16_t* __restrict__ x, const float* __restrict__ cache,
    const float* __restrict__ cw, bf16_t* __restrict__ m,
    float* __restrict__ oc) {
    __shared__ float sx[(TT + HALO) * PPT];   // 83*128*4 = 42.5 KB

    const int tid = threadIdx.x;
    const int t0  = blockIdx.x * TT;
    const int b   = blockIdx.y;
    const int p0  = blockIdx.z * PPT;

    // ---- stage rows t0-19 .. t0+63, cols p0..p0+127 (8 bf16 per chunk) ----
    for (int c = tid; c < (TT + HALO) * PPT / 8; c += 256) {   // 1328 chunks
        int r    = c >> 4;            // 0..82
        int col  = (c & 15) << 3;     // 0,8,...,120
        int trow = t0 - HALO + r;
        float* dst = sx + r * PPT + col;
        if (trow >= 0) {
            bf16x8 v = *(const bf16x8*)(x + ((size_t)(b * T_ + trow)) * DPJ + p0 + col);
#pragma unroll
            for (int i = 0; i < 8; ++i) dst[i] = (float)v[i];
        } else {
#pragma unroll
            for (int i = 0; i < 8; ++i)
                dst[i] = cache[((size_t)b * DPJ + p0 + col + i) * HALO + (trow + HALO)];
        }
    }
    __syncthreads();

    // ---- compute: thread -> channel pair, 16 timesteps, rolling window ----
    const int pp   = tid & 63;
    const int half = tid >> 6;
    const int tb   = half * 16;
    const float2* sx2 = (const float2*)sx;   // [83][64]

    const int pg = p0 + 2 * pp;
    float2 w[LORD];
#pragma unroll
    for (int l = 0; l < LORD; ++l) {
        w[l].x = cw[pg * LORD + l];
        w[l].y = cw[(pg + 1) * LORD + l];
    }

    float2 win[LORD];
#pragma unroll
    for (int i = 0; i < HALO; ++i) win[i] = sx2[(tb + i) * 64 + pp];

#pragma unroll
    for (int tl = 0; tl < 16; ++tl) {
        float2 nv = sx2[(tb + tl + HALO) * 64 + pp];
        win[(tl + HALO) % LORD] = nv;
        float2 s = nv;                         // residual x[b,t,p]
#pragma unroll
        for (int l = 0; l < LORD; ++l) {
            float2 v = win[(tl + l) % LORD];
            s.x += w[l].x * v.x;
            s.y += w[l].y * v.y;
        }
        bf16x2 o = { (bf16_t)s.x, (bf16_t)s.y };
        *(bf16x2*)(m + ((size_t)(b * T_ + t0 + tb + tl)) * DPJ + pg) = o;
    }

    // ---- fused out_cache: out_cache[b,p,j] = x[b, T-19+j, p], from LDS ----
    if (blockIdx.x == (T_ / TT) - 1) {
        for (int i = tid; i < PPT * HALO; i += 256) {
            int pl = i / HALO;
            int j  = i - pl * HALO;
            oc[((size_t)b * DPJ + p0 + pl) * HALO + j] = sx[(64 + j) * PPT + pl];
        }
    }
}

// ---------------------------------------------------------------------------
extern "C" void kernel_launch(void* const* d_in, const int* in_sizes, int n_in,
                              void* d_out, int out_size, void* d_ws, size_t ws_size,
                              hipStream_t stream) {
    const float* input    = (const float*)d_in[0];  // (16,2048,1024)
    const float* in_cache = (const float*)d_in[1];  // (16,512,19)
    const float* W_lin    = (const float*)d_in[2];  // (1024,512)
    const float* conv_w   = (const float*)d_in[3];  // (512,20)
    const float* W_aff    = (const float*)d_in[4];  // (512,1024)
    const float* b_aff    = (const float*)d_in[5];  // (1024,)
    float* out = (float*)d_out;                     // 33554432 + 155648 f32

    // workspace layout (bytes):
    //   [0, 32MB)       x bf16 (32768x512)
    //   [32MB, 64MB)    m bf16 (32768x512)
    //   [64MB, +1MB)    W_lin^T bf16 (512x1024)
    //   [65MB, +0.5MB)  W_aff^T bf16 (1024x512)
    char* ws = (char*)d_ws;
    bf16_t* x_buf = (bf16_t*)(ws);
    bf16_t* m_buf = (bf16_t*)(ws + 33554432);
    bf16_t* WlinT = (bf16_t*)(ws + 67108864);
    bf16_t* WaffT = (bf16_t*)(ws + 67108864 + 1048576);

    // 1. weight prep (both transposes, one launch, coalesced writes)
    prep_weights<<<(DIN * DPJ + DPJ * DOUT + 255) / 256, 256, 0, stream>>>(
        W_lin, W_aff, WlinT, WaffT);

    // 2. x = bf16(input) @ W_lin   (M=32768, N=512, K=1024), dbuf pipeline
    gemm1_fused<<<dim3(DPJ / 128, M_ROWS / 128), 512, 0, stream>>>(
        input, WlinT, x_buf, M_ROWS, DPJ, DIN);

    // 3. depthwise conv + residual -> m ; out_cache fused into last-t blocks
    dwconv_tiled<<<dim3(T_ / TT, B_, DPJ / PPT), 256, 0, stream>>>(
        x_buf, in_cache, conv_w, m_buf, out + OUT0_ELEMS);

    // 4. out = relu(m @ W_aff + b)  (M=32768, N=1024, K=512), dbuf pipeline
    gemm_bt_relu<<<dim3(DOUT / 128, M_ROWS / 128), 256, 0, stream>>>(
        m_buf, WaffT, out, b_aff, M_ROWS, DOUT, DPJ);
}

// Round 7
// 332.698 us; speedup vs baseline: 1.0936x; 1.0592x over previous
//
#include <hip/hip_runtime.h>
#include <cstdint>
#include <cstddef>

// Problem constants
#define B_  16
#define T_  2048
#define DIN 1024
#define DPJ 512
#define DOUT 1024
#define LORD 20
#define HALO (LORD - 1)             // 19
#define M_ROWS (B_ * T_)            // 32768
#define OUT0_ELEMS ((size_t)M_ROWS * DOUT)          // 33554432
#define CACHE_ELEMS ((size_t)B_ * DPJ * (LORD - 1)) // 155648

typedef __bf16 bf16_t;
typedef __bf16 bf16x2 __attribute__((ext_vector_type(2)));
typedef __bf16 bf16x4 __attribute__((ext_vector_type(4)));
typedef __bf16 bf16x8 __attribute__((ext_vector_type(8)));
typedef float  f32x4  __attribute__((ext_vector_type(4)));

// ---------------------------------------------------------------------------
// async global->LDS, 16B per lane. lds pointer must be wave-uniform; HW puts
// lane i's 16B at lds_base + i*16.
__device__ __forceinline__ void async_load16(const void* g, void* lds_base) {
    __builtin_amdgcn_global_load_lds(
        (const __attribute__((address_space(1))) unsigned int*)g,
        (__attribute__((address_space(3))) unsigned int*)lds_base,
        16, 0, 0);
}

// ---------------------------------------------------------------------------
// XCD-aware bijective block swizzle (T1). Round-1 evidence: FETCH_SIZE
// 265MB -> 74MB on gemm1. Keep. Requires nwg % 8 == 0 (1024/2048 here).
__device__ __forceinline__ int xcd_swizzle(int hw, int nwg) {
    int cpx = nwg >> 3;                  // chunk per XCD
    return (hw & 7) * cpx + (hw >> 3);
}

// ---------------------------------------------------------------------------
// Weight transposes, output-indexed (coalesced 2B writes; strided 4B reads
// are L2-resident).
__global__ __launch_bounds__(256) void prep_weights(
    const float* __restrict__ Wl, const float* __restrict__ Wa,
    bf16_t* __restrict__ WlT, bf16_t* __restrict__ WaT) {
    int idx = blockIdx.x * 256 + threadIdx.x;
    const int n1 = DIN * DPJ;
    if (idx < n1) {
        int n = idx >> 10;               // /DIN
        int k = idx - (n << 10);
        WlT[idx] = (bf16_t)Wl[(size_t)k * DPJ + n];
    } else {
        int j = idx - n1;
        if (j < DPJ * DOUT) {
            int n = j >> 9;              // /DPJ
            int k = j - (n << 9);
            WaT[j] = (bf16_t)Wa[(size_t)k * DOUT + n];
        }
    }
}

// ---------------------------------------------------------------------------
// FUSED GEMM1 + depthwise conv + residual.
//   x = bf16(input) @ W_lin  (per-block tile: 160 t-rows x 128 channels,
//   rows t0-32..t0+127 — 19-row halo recomputed, +25% M work, zero
//   cross-block duplication since conv is per-channel and N-dim = channels)
//   then in-LDS conv (taps=20, causal) + residual -> m written directly.
//   x never touches global memory (round-7: eliminates dwconv kernel and
//   64 MB of intermediate traffic).
// K-loop: round-6 double-buffered pipeline, single A reg set P (WAR-safe:
// new loads issue after cvt consumes), counted vmcnt(5) = keep 5 A loads
// in flight, drain 2 B DMAs issued one full phase earlier.
#define XR 160          // LDS x rows (t0-32 .. t0+127)
#define PADC 136        // padded channel stride for conv-phase LDS
__global__ __launch_bounds__(512, 4) void gemm1_conv(
    const float* __restrict__ A, const bf16_t* __restrict__ Bt,
    const float* __restrict__ cache, const float* __restrict__ cw,
    bf16_t* __restrict__ m, float* __restrict__ oc) {
    // LDS carve (72 KB): staging dbuf while K-loop runs; x-tile after.
    __shared__ __align__(16) char ldsraw[73728];
    bf16_t* sA0 = (bf16_t*)(ldsraw);            // 160*64*2 = 20480
    bf16_t* sA1 = (bf16_t*)(ldsraw + 20480);    // 20480
    bf16_t* sB0 = (bf16_t*)(ldsraw + 40960);    // 128*64*2 = 16384
    bf16_t* sB1 = (bf16_t*)(ldsraw + 57344);    // 16384 -> 73728
    bf16_t* xb  = (bf16_t*)(ldsraw);            // [160][136] = 43520 (aliases)

    const int tid  = threadIdx.x;
    const int lane = tid & 63;
    const int wave = tid >> 6;           // 0..7
    const int K    = DIN;

    const int gx   = gridDim.x;          // 4
    const int hw   = blockIdx.y * gx + blockIdx.x;
    const int lid  = xcd_swizzle(hw, gx * gridDim.y);
    const int lby  = lid / gx;           // M tile 0..255
    const int lbx  = lid - lby * gx;
    const int col0 = lbx * 128;          // channel tile
    const int b    = lby >> 4;           // batch
    const int tloc = (lby & 15) * 128;   // t0 within batch
    const float* Ab = A + (size_t)b * T_ * DIN;

    // ---- A staging: 5 f32x4 units/thread, u = tid + 512*i ----
    // row r = u>>4 (0..159), c16 = u&15 (16B chunk in 64-col window).
    // t = tloc-32+r, clamped >=0 (clamped rows are dead halo, r<13).
    // Swizzled dest: bf16 chunk j=c16>>1 at (j^(r&7)), half (c16&1).
    size_t aoff[5];
    int    doff[5];
#pragma unroll
    for (int i = 0; i < 5; ++i) {
        int u = tid + 512 * i;
        int r = u >> 4, c16 = u & 15;
        int t = tloc - 32 + r; if (t < 0) t = 0;
        aoff[i] = (size_t)t * DIN + c16 * 4;
        doff[i] = r * 64 + (((c16 >> 1) ^ (r & 7)) << 3) + (c16 & 1) * 4;
    }

    // ---- B staging: 2 async calls/lane; wave w rows w*16 + c*8 + lr ----
    const int lr  = lane >> 3;
    const int jsw = (lane & 7) ^ lr;
    const bf16_t* gB0 = Bt + (size_t)(col0 + wave * 16 + lr) * K + jsw * 8;

    // compute-side: wave -> 80x32 sub-tile (2M x 4N), M extent 160
    const int wm = (wave >> 2) * 80;
    const int wn = (wave & 3) * 32;
    const int fr = lane & 15;
    const int fk = lane >> 4;

    const f32x4 zero = {0.f, 0.f, 0.f, 0.f};
    f32x4 acc[5][2];
#pragma unroll
    for (int mt = 0; mt < 5; ++mt)
#pragma unroll
        for (int nt = 0; nt < 2; ++nt) acc[mt][nt] = zero;

    f32x4 P[5];
    auto load_a = [&](int kk) {
#pragma unroll
        for (int i = 0; i < 5; ++i) P[i] = *(const f32x4*)(Ab + aoff[i] + kk);
    };
    auto cvt_write = [&](bf16_t* dst) {
#pragma unroll
        for (int i = 0; i < 5; ++i) {
            bf16x4 v = { (bf16_t)P[i][0], (bf16_t)P[i][1],
                         (bf16_t)P[i][2], (bf16_t)P[i][3] };
            *(bf16x4*)(dst + doff[i]) = v;
        }
    };
    auto stage_b = [&](int kk, bf16_t* dstB) {
#pragma unroll
        for (int c = 0; c < 2; ++c)
            async_load16(gB0 + (size_t)c * 8 * K + kk, dstB + wave * 1024 + c * 512);
    };
    auto compute = [&](const bf16_t* bA, const bf16_t* bB) {
#pragma unroll
        for (int h = 0; h < 2; ++h) {
            bf16x8 af[5], bfr[2];
#pragma unroll
            for (int mt = 0; mt < 5; ++mt) {
                int r = wm + mt * 16 + fr;
                int j = h * 4 + fk;
                af[mt] = *(const bf16x8*)(bA + r * 64 + ((j ^ (r & 7)) << 3));
            }
#pragma unroll
            for (int nt = 0; nt < 2; ++nt) {
                int r = wn + nt * 16 + fr;
                int j = h * 4 + fk;
                bfr[nt] = *(const bf16x8*)(bB + r * 64 + ((j ^ (r & 7)) << 3));
            }
#pragma unroll
            for (int mt = 0; mt < 5; ++mt)
#pragma unroll
                for (int nt = 0; nt < 2; ++nt)
                    acc[mt][nt] = __builtin_amdgcn_mfma_f32_16x16x32_bf16(
                        af[mt], bfr[nt], acc[mt][nt], 0, 0, 0);
        }
    };

    // ---- prologue: tile 0 -> buf0; A(1) -> P ----
    load_a(0);
    stage_b(0, sB0);
    cvt_write(sA0);      // waits A(0) only (B DMAs newer, stay in flight)
    load_a(64);          // A(1)

    // steady state at iter top: outstanding = 2 B (old) + 5 A (new).
    for (int k0 = 0; k0 < K; k0 += 128) {
        // ---- even tile t: compute buf0, stage t+1 -> buf1 ----
        asm volatile("s_waitcnt vmcnt(5) lgkmcnt(0)" ::: "memory");
        __builtin_amdgcn_sched_barrier(0);
        __builtin_amdgcn_s_barrier();
        __builtin_amdgcn_sched_barrier(0);
        stage_b(k0 + 64, sB1);           // k0+64 < K always
        cvt_write(sA1);                  // consumes P=A(t+1)
        if (k0 + 128 < K) load_a(k0 + 128);   // P <- A(t+2) (WAR-safe)
        compute(sA0, sB0);

        // ---- odd tile t+1: compute buf1, stage t+2 -> buf0 ----
        if (k0 + 128 < K) {
            asm volatile("s_waitcnt vmcnt(5) lgkmcnt(0)" ::: "memory");
        } else {
            asm volatile("s_waitcnt vmcnt(0) lgkmcnt(0)" ::: "memory");
        }
        __builtin_amdgcn_sched_barrier(0);
        __builtin_amdgcn_s_barrier();
        __builtin_amdgcn_sched_barrier(0);
        if (k0 + 128 < K) {
            stage_b(k0 + 128, sB0);
            cvt_write(sA0);
            if (k0 + 192 < K) load_a(k0 + 192);
        }
        compute(sA1, sB1);
    }

    // ================= fused conv epilogue =================
    // 1. x-tile (bf16) -> LDS [160][PADC]
    __syncthreads();     // all LDS staging reads done; safe to overwrite
    {
        const int er_l = wm + (lane >> 4) * 4;
        const int ec_l = wn + (lane & 15);
#pragma unroll
        for (int mt = 0; mt < 5; ++mt)
#pragma unroll
            for (int nt = 0; nt < 2; ++nt)
#pragma unroll
                for (int rr = 0; rr < 4; ++rr)
                    xb[(er_l + mt * 16 + rr) * PADC + ec_l + nt * 16] =
                        (bf16_t)acc[mt][nt][rr];
    }
    __syncthreads();

    // 2. first-tile halo: rows 13..31 (t=-19..-1) <- in_cache[b][p][j]
    if (tloc == 0) {
        for (int i2 = tid; i2 < HALO * 128; i2 += 512) {
            int rr2 = i2 >> 7;            // 0..18
            int cc  = i2 & 127;
            xb[(13 + rr2) * PADC + cc] =
                (bf16_t)cache[((size_t)b * DPJ + col0 + cc) * HALO + rr2];
        }
    }
    __syncthreads();

    // 3. conv + residual -> m.  Thread: 2 channels x 16 timesteps.
    //    Output local t needs LDS rows t+13 .. t+32.
    {
        const int pp   = tid & 63;
        const int tb   = (tid >> 6) * 16;
        const int pg_l = 2 * pp;
        const int pg   = col0 + pg_l;

        float2 w[LORD];
#pragma unroll
        for (int l = 0; l < LORD; ++l) {
            w[l].x = cw[pg * LORD + l];
            w[l].y = cw[(pg + 1) * LORD + l];
        }
        auto rdx = [&](int r) -> float2 {
            bf16x2 v = *(const bf16x2*)(xb + r * PADC + pg_l);
            float2 f; f.x = (float)v[0]; f.y = (float)v[1]; return f;
        };
        float2 win[LORD];
#pragma unroll
        for (int i = 0; i < HALO; ++i) win[i] = rdx(tb + 13 + i);
#pragma unroll
        for (int tl = 0; tl < 16; ++tl) {
            float2 nv = rdx(tb + 13 + tl + HALO);   // x[t]
            win[(tl + HALO) % LORD] = nv;
            float2 s = nv;                          // residual
#pragma unroll
            for (int l = 0; l < LORD; ++l) {
                float2 v = win[(tl + l) % LORD];
                s.x += w[l].x * v.x;
                s.y += w[l].y * v.y;
            }
            bf16x2 o = { (bf16_t)s.x, (bf16_t)s.y };
            *(bf16x2*)(m + ((size_t)(b * T_ + tloc + tb + tl)) * DPJ + pg) = o;
        }
    }

    // 4. out_cache from last t-tile: oc[b][p][j] = x[b, T-19+j, p]
    //    (LDS rows 141..159)
    if (tloc == T_ - 128) {
        for (int i2 = tid; i2 < 128 * HALO; i2 += 512) {
            int pl = i2 / HALO;
            int j  = i2 - pl * HALO;
            oc[((size_t)b * DPJ + col0 + pl) * HALO + j] =
                (float)xb[(141 + j) * PADC + pl];
        }
    }
}

// ---------------------------------------------------------------------------
// GEMM2: bf16 A (async staging), f32 out with bias+ReLU.  Round-6 dbuf
// 1-barrier pipeline, unchanged.
__global__ __launch_bounds__(256) void gemm_bt_relu(
    const bf16_t* __restrict__ A, const bf16_t* __restrict__ Bt,
    float* __restrict__ C, const float* __restrict__ bias,
    const int M, const int N, const int K) {
    __shared__ bf16_t sA[2][128 * 64];
    __shared__ bf16_t sB[2][128 * 64];

    const int tid  = threadIdx.x;
    const int lane = tid & 63;
    const int wave = tid >> 6;           // 0..3

    const int gx   = gridDim.x;
    const int hw   = blockIdx.y * gx + blockIdx.x;
    const int lid  = xcd_swizzle(hw, gx * gridDim.y);
    const int lby  = lid / gx;
    const int lbx  = lid - lby * gx;
    const int col0 = lbx * 128;          // N tile
    const int row0 = lby * 128;          // M tile

    const int lr   = lane >> 3;
    const int jsw  = (lane & 7) ^ lr;
    const bf16_t* gA0 = A  + (size_t)(row0 + wave * 32 + lr) * K + jsw * 8;
    const bf16_t* gB0 = Bt + (size_t)(col0 + wave * 32 + lr) * K + jsw * 8;

    const int wm = (wave >> 1) * 64;
    const int wn = (wave & 1) * 64;
    const int fr = lane & 15;
    const int fk = lane >> 4;

    const f32x4 zero = {0.f, 0.f, 0.f, 0.f};
    f32x4 acc[4][4];
#pragma unroll
    for (int mt = 0; mt < 4; ++mt)
#pragma unroll
        for (int nt = 0; nt < 4; ++nt) acc[mt][nt] = zero;

    auto stage = [&](int kk, bf16_t* dA, bf16_t* dB) {
#pragma unroll
        for (int c = 0; c < 4; ++c) {
            async_load16(gA0 + (size_t)c * 8 * K + kk, dA + wave * 2048 + c * 512);
            async_load16(gB0 + (size_t)c * 8 * K + kk, dB + wave * 2048 + c * 512);
        }
    };
    auto compute = [&](const bf16_t* bA, const bf16_t* bB) {
#pragma unroll
        for (int h = 0; h < 2; ++h) {
            bf16x8 af[4], bfr[4];
#pragma unroll
            for (int mt = 0; mt < 4; ++mt) {
                int r = wm + mt * 16 + fr;
                int j = h * 4 + fk;
                af[mt] = *(const bf16x8*)(bA + r * 64 + ((j ^ (r & 7)) << 3));
            }
#pragma unroll
            for (int nt = 0; nt < 4; ++nt) {
                int r = wn + nt * 16 + fr;
                int j = h * 4 + fk;
                bfr[nt] = *(const bf16x8*)(bB + r * 64 + ((j ^ (r & 7)) << 3));
            }
#pragma unroll
            for (int mt = 0; mt < 4; ++mt)
#pragma unroll
                for (int nt = 0; nt < 4; ++nt)
                    acc[mt][nt] = __builtin_amdgcn_mfma_f32_16x16x32_bf16(
                        af[mt], bfr[nt], acc[mt][nt], 0, 0, 0);
        }
    };

    stage(0, sA[0], sB[0]);

    for (int k0 = 0; k0 < K; k0 += 128) {
        asm volatile("s_waitcnt vmcnt(0)" ::: "memory");
        __builtin_amdgcn_sched_barrier(0);
        __builtin_amdgcn_s_barrier();
        __builtin_amdgcn_sched_barrier(0);
        stage(k0 + 64, sA[1], sB[1]);        // k0+64 < K always
        compute(sA[0], sB[0]);

        asm volatile("s_waitcnt vmcnt(0)" ::: "memory");
        __builtin_amdgcn_sched_barrier(0);
        __builtin_amdgcn_s_barrier();
        __builtin_amdgcn_sched_barrier(0);
        const int kn2 = k0 + 128;
        if (kn2 < K) stage(kn2, sA[0], sB[0]);
        compute(sA[1], sB[1]);
    }

    const int er = row0 + wm + (lane >> 4) * 4;
    const int ec = col0 + wn + (lane & 15);
#pragma unroll
    for (int nt = 0; nt < 4; ++nt) {
        float bb = bias[ec + nt * 16];
#pragma unroll
        for (int mt = 0; mt < 4; ++mt)
#pragma unroll
            for (int rr = 0; rr < 4; ++rr) {
                float v = acc[mt][nt][rr] + bb;
                C[(size_t)(er + mt * 16 + rr) * N + (ec + nt * 16)] =
                    v > 0.f ? v : 0.f;
            }
    }
}

// ---------------------------------------------------------------------------
extern "C" void kernel_launch(void* const* d_in, const int* in_sizes, int n_in,
                              void* d_out, int out_size, void* d_ws, size_t ws_size,
                              hipStream_t stream) {
    const float* input    = (const float*)d_in[0];  // (16,2048,1024)
    const float* in_cache = (const float*)d_in[1];  // (16,512,19)
    const float* W_lin    = (const float*)d_in[2];  // (1024,512)
    const float* conv_w   = (const float*)d_in[3];  // (512,20)
    const float* W_aff    = (const float*)d_in[4];  // (512,1024)
    const float* b_aff    = (const float*)d_in[5];  // (1024,)
    float* out = (float*)d_out;                     // 33554432 + 155648 f32

    // workspace layout (bytes):
    //   [32MB, 64MB)    m bf16 (32768x512)
    //   [64MB, +1MB)    W_lin^T bf16 (512x1024)
    //   [65MB, +0.5MB)  W_aff^T bf16 (1024x512)
    char* ws = (char*)d_ws;
    bf16_t* m_buf = (bf16_t*)(ws + 33554432);
    bf16_t* WlinT = (bf16_t*)(ws + 67108864);
    bf16_t* WaffT = (bf16_t*)(ws + 67108864 + 1048576);

    // 1. weight prep (both transposes, one launch, coalesced writes)
    prep_weights<<<(DIN * DPJ + DPJ * DOUT + 255) / 256, 256, 0, stream>>>(
        W_lin, W_aff, WlinT, WaffT);

    // 2. fused: x = bf16(input) @ W_lin ; depthwise conv + residual -> m ;
    //    out_cache from last-t blocks.  (dwconv kernel eliminated.)
    gemm1_conv<<<dim3(DPJ / 128, M_ROWS / 128), 512, 0, stream>>>(
        input, WlinT, in_cache, conv_w, m_buf, out + OUT0_ELEMS);

    // 3. out = relu(m @ W_aff + b)  (M=32768, N=1024, K=512), dbuf pipeline
    gemm_bt_relu<<<dim3(DOUT / 128, M_ROWS / 128), 256, 0, stream>>>(
        m_buf, WaffT, out, b_aff, M_ROWS, DOUT, DPJ);
}